// Round 1
// baseline (201.121 us; speedup 1.0000x reference)
//
#include <hip/hip_runtime.h>
#include <math.h>

// ---- Problem constants (baked into the reference) ----
#define NATOM 4096
#define KX 14
#define KY 15
#define KZ 16
#define NGRID (KX*KY*KZ)          // 3360
// ws layout: float grid[3360] at byte 0; double acc[2] at byte 13440 (8-aligned)
//   acc[0] = raw direct-pair sum (before 0.5*C scale)
//   acc[1] = sum_m green*B*|F|^2
#define ACC_BYTE_OFF 13440
#define WS_WORDS ((ACC_BYTE_OFF + 16) / 4)   // 3364 32-bit words to zero

static constexpr float ALPHA_F   = 4.985823141035867f;
static constexpr float COULOMB_F = 138.935f;
static constexpr float CUT2_F    = 0.25f;    // CUTOFF^2
static constexpr float TWOPI_F   = 6.283185307179586f;
static constexpr float PI_F      = 3.14159265358979f;

// ---- Cardinal B-spline M5 via the Essmann recursion (matches reference _M) ----
__device__ __forceinline__ float M1f(float x){ return (x >= 0.f && x < 1.f) ? 1.f : 0.f; }
__device__ __forceinline__ float M2f(float x){ return x*M1f(x) + (2.f-x)*M1f(x-1.f); }
__device__ __forceinline__ float M3f(float x){ return (x*M2f(x) + (3.f-x)*M2f(x-1.f)) * 0.5f; }
__device__ __forceinline__ float M4f(float x){ return (x*M3f(x) + (4.f-x)*M3f(x-1.f)) * (1.f/3.f); }
__device__ __forceinline__ float M5f(float x){ return (x*M4f(x) + (5.f-x)*M4f(x-1.f)) * 0.25f; }

// ---- 3x3 inverse (general, though test box is diagonal) ----
__device__ __forceinline__ void inv3x3(const float* b, float* inv){
  float det = b[0]*(b[4]*b[8]-b[5]*b[7]) - b[1]*(b[3]*b[8]-b[5]*b[6]) + b[2]*(b[3]*b[7]-b[4]*b[6]);
  float id = 1.f/det;
  inv[0] = (b[4]*b[8]-b[5]*b[7])*id;
  inv[1] = (b[2]*b[7]-b[1]*b[8])*id;
  inv[2] = (b[1]*b[5]-b[2]*b[4])*id;
  inv[3] = (b[5]*b[6]-b[3]*b[8])*id;
  inv[4] = (b[0]*b[8]-b[2]*b[6])*id;
  inv[5] = (b[2]*b[3]-b[0]*b[5])*id;
  inv[6] = (b[3]*b[7]-b[4]*b[6])*id;
  inv[7] = (b[1]*b[6]-b[0]*b[7])*id;
  inv[8] = (b[0]*b[4]-b[1]*b[3])*id;
}

// |b(m)|^-2 per axis; M5 at integers 1..4 = {1,11,11,1}/24
__device__ __forceinline__ float bmod(int m, int K){
  float base = TWOPI_F * (float)m / (float)K;
  float s, c;
  float dr = 1.f/24.f, di = 0.f;
  sincosf(base,      &s, &c); dr += (11.f/24.f)*c; di += (11.f/24.f)*s;
  sincosf(base*2.f,  &s, &c); dr += (11.f/24.f)*c; di += (11.f/24.f)*s;
  sincosf(base*3.f,  &s, &c); dr += (1.f/24.f)*c;  di += (1.f/24.f)*s;
  float d2 = dr*dr + di*di;
  return (d2 < 1e-7f) ? 0.f : 1.f/d2;
}

// ---- zero the workspace (grid + double accumulators) ----
__global__ __launch_bounds__(256) void zero_ws(unsigned int* __restrict__ ws){
  int i = blockIdx.x*256 + threadIdx.x;
  if (i < WS_WORDS) ws[i] = 0u;
}

// ---- charge spreading: per-block LDS privatized grid, then global atomics ----
__global__ __launch_bounds__(256) void spread_kernel(const float* __restrict__ pos,
    const float* __restrict__ chg, const float* __restrict__ box, float* __restrict__ grid)
{
  __shared__ float sg[NGRID];
  for (int i = threadIdx.x; i < NGRID; i += 256) sg[i] = 0.f;
  __syncthreads();

  float b[9], inv[9];
  #pragma unroll
  for (int i = 0; i < 9; ++i) b[i] = box[i];
  inv3x3(b, inv);

  int atom = blockIdx.x*256 + threadIdx.x;
  float px = pos[atom*3+0], py = pos[atom*3+1], pz = pos[atom*3+2];
  float qi = chg[atom];
  // fractional coords: row-vector pos @ inv(box)
  float fr[3];
  fr[0] = px*inv[0] + py*inv[3] + pz*inv[6];
  fr[1] = px*inv[1] + py*inv[4] + pz*inv[7];
  fr[2] = px*inv[2] + py*inv[5] + pz*inv[8];

  const int Ks[3] = {KX, KY, KZ};
  float w[3][5]; int id[3][5];
  #pragma unroll
  for (int a = 0; a < 3; ++a) {
    float f = fr[a] - floorf(fr[a]);
    float u = f * (float)Ks[a];
    float bse = floorf(u);
    float x = u - bse;
    int bi = (int)bse;
    #pragma unroll
    for (int j = 0; j < 5; ++j) {
      w[a][j] = M5f(x + (float)j);           // weight for grid point (base - j)
      int ii = bi - j; if (ii < 0) ii += Ks[a];
      id[a][j] = ii;
    }
  }
  #pragma unroll
  for (int jx = 0; jx < 5; ++jx) {
    float qx = qi * w[0][jx];
    int ox = id[0][jx]*(KY*KZ);
    #pragma unroll
    for (int jy = 0; jy < 5; ++jy) {
      float qxy = qx * w[1][jy];
      int oxy = ox + id[1][jy]*KZ;
      #pragma unroll
      for (int jz = 0; jz < 5; ++jz)
        atomicAdd(&sg[oxy + id[2][jz]], qxy * w[2][jz]);
    }
  }
  __syncthreads();
  for (int i = threadIdx.x; i < NGRID; i += 256) {
    float v = sg[i];
    if (v != 0.f) atomicAdd(&grid[i], v);
  }
}

// ---- reciprocal mode sum: one thread per (my,mz), block per mx; brute separable DFT ----
__global__ __launch_bounds__(256) void modesum_kernel(const float* __restrict__ grid,
    const float* __restrict__ box, double* __restrict__ acc)
{
  __shared__ float sq[NGRID];
  __shared__ double red[256];
  for (int i = threadIdx.x; i < NGRID; i += 256) sq[i] = grid[i];
  __syncthreads();

  int t = threadIdx.x;
  double contrib = 0.0;
  if (t < KY*KZ) {
    int mx = blockIdx.x;
    int my = t / KZ;
    int mz = t % KZ;
    // fftfreq(K)*K: index i -> i for i <= (K-1)/2 else i-K
    float fx = (mx <= (KX-1)/2) ? (float)mx : (float)(mx - KX);
    float fy = (my <= (KY-1)/2) ? (float)my : (float)(my - KY);
    float fz = (mz <= (KZ-1)/2) ? (float)mz : (float)(mz - KZ);

    float b[9], inv[9];
    #pragma unroll
    for (int i = 0; i < 9; ++i) b[i] = box[i];
    inv3x3(b, inv);
    // mv[k] = fx*recip[k][0] + fy*recip[k][1] + fz*recip[k][2]
    float mv0 = fx*inv[0] + fy*inv[1] + fz*inv[2];
    float mv1 = fx*inv[3] + fy*inv[4] + fz*inv[5];
    float mv2 = fx*inv[6] + fy*inv[7] + fz*inv[8];
    float m2 = mv0*mv0 + mv1*mv1 + mv2*mv2;
    float B  = bmod(mx,KX) * bmod(my,KY) * bmod(mz,KZ);

    if (m2 > 0.f && B != 0.f) {
      float green = expf(-(PI_F*PI_F)*m2/(ALPHA_F*ALPHA_F)) / m2;
      // per-mode twiddle tables (exact phase via (m*g) mod K)
      float cxr[KX], cxi[KX], cyr[KY], cyi[KY], czr[KZ], czi[KZ];
      for (int g = 0; g < KX; ++g){ float s,c; sincosf(-TWOPI_F*(float)((mx*g)%KX)/(float)KX, &s,&c); cxr[g]=c; cxi[g]=s; }
      for (int g = 0; g < KY; ++g){ float s,c; sincosf(-TWOPI_F*(float)((my*g)%KY)/(float)KY, &s,&c); cyr[g]=c; cyi[g]=s; }
      for (int g = 0; g < KZ; ++g){ float s,c; sincosf(-TWOPI_F*(float)((mz*g)%KZ)/(float)KZ, &s,&c); czr[g]=c; czi[g]=s; }

      float Fr = 0.f, Fi = 0.f;
      for (int gx = 0; gx < KX; ++gx){
        float ar = 0.f, ai = 0.f;
        const float* rowx = &sq[gx*(KY*KZ)];
        for (int gy = 0; gy < KY; ++gy){
          float br = 0.f, bi2 = 0.f;
          const float* rowy = rowx + gy*KZ;
          #pragma unroll
          for (int gz = 0; gz < KZ; ++gz){
            float qv = rowy[gz];
            br  += qv * czr[gz];
            bi2 += qv * czi[gz];
          }
          ar += br*cyr[gy] - bi2*cyi[gy];
          ai += br*cyi[gy] + bi2*cyr[gy];
        }
        Fr += ar*cxr[gx] - ai*cxi[gx];
        Fi += ar*cxi[gx] + ai*cxr[gx];
      }
      contrib = (double)(green*B) * ((double)Fr*(double)Fr + (double)Fi*(double)Fi);
    }
  }
  red[t] = contrib;
  __syncthreads();
  for (int s = 128; s > 0; s >>= 1){ if (t < s) red[t] += red[t+s]; __syncthreads(); }
  if (t == 0) atomicAdd(&acc[1], red[0]);
}

// ---- direct space: 16x16 tiles of 256x256 pairs, j-tile staged in LDS ----
__global__ __launch_bounds__(256) void direct_kernel(const float* __restrict__ pos,
    const float* __restrict__ chg, const float* __restrict__ box, double* __restrict__ acc)
{
  __shared__ float sx[256], sy[256], sz[256], sw[256];
  __shared__ double red[256];
  int t  = threadIdx.x;
  int i  = blockIdx.x*256 + t;
  int j0 = blockIdx.y*256;
  int j  = j0 + t;
  sx[t] = pos[j*3+0]; sy[t] = pos[j*3+1]; sz[t] = pos[j*3+2]; sw[t] = chg[j];
  __syncthreads();

  float b00=box[0],b01=box[1],b02=box[2],
        b10=box[3],b11=box[4],b12=box[5],
        b20=box[6],b21=box[7],b22=box[8];
  float i00 = 1.f/b00, i11 = 1.f/b11, i22 = 1.f/b22;

  float xi = pos[i*3+0], yi = pos[i*3+1], zi = pos[i*3+2], qi = chg[i];
  float e = 0.f;
  for (int jj = 0; jj < 256; ++jj){
    float dx = xi - sx[jj], dy = yi - sy[jj], dz = zi - sz[jj];
    // triclinic-reduced minimum image, axes 2,1,0 (rintf == round-half-even)
    float t2 = rintf(dz * i22); dx -= b20*t2; dy -= b21*t2; dz -= b22*t2;
    float t1 = rintf(dy * i11); dx -= b10*t1; dy -= b11*t1; dz -= b12*t1;
    float t0 = rintf(dx * i00); dx -= b00*t0; dy -= b01*t0; dz -= b02*t0;
    float r2 = dx*dx + dy*dy + dz*dz;
    if (r2 < CUT2_F && (j0 + jj) != i){
      float r = sqrtf(r2);
      e += qi * sw[jj] * erfcf(ALPHA_F * r) / r;
    }
  }
  red[t] = (double)e;
  __syncthreads();
  for (int k = 128; k > 0; k >>= 1){ if (t < k) red[t] += red[t+k]; __syncthreads(); }
  if (t == 0) atomicAdd(&acc[0], red[0]);
}

// ---- finalize: sum q^2, combine all terms, write scalar ----
__global__ __launch_bounds__(256) void finalize_kernel(const float* __restrict__ chg,
    const float* __restrict__ box, const double* __restrict__ acc, float* __restrict__ out)
{
  __shared__ double red[256];
  int t = threadIdx.x;
  double s = 0.0;
  for (int i = t; i < NATOM; i += 256){ double q = (double)chg[i]; s += q*q; }
  red[t] = s;
  __syncthreads();
  for (int k = 128; k > 0; k >>= 1){ if (t < k) red[t] += red[t+k]; __syncthreads(); }
  if (t == 0){
    double b00=box[0],b01=box[1],b02=box[2],
           b10=box[3],b11=box[4],b12=box[5],
           b20=box[6],b21=box[7],b22=box[8];
    double det = b00*(b11*b22 - b12*b21) - b01*(b10*b22 - b12*b20) + b02*(b10*b21 - b11*b20);
    double V = fabs(det);
    const double PI_D = 3.141592653589793238462643;
    double edir  = 0.5 * (double)COULOMB_F * acc[0];
    double erec  = (double)COULOMB_F / (2.0*PI_D*V) * acc[1];
    double eself = -(double)COULOMB_F * 4.985823141035867 / sqrt(PI_D) * red[0];
    out[0] = (float)(edir - erec - eself);
  }
}

extern "C" void kernel_launch(void* const* d_in, const int* in_sizes, int n_in,
                              void* d_out, int out_size, void* d_ws, size_t ws_size,
                              hipStream_t stream) {
  const float* pos = (const float*)d_in[0];   // [4096,3] f32
  const float* chg = (const float*)d_in[1];   // [4096]   f32
  const float* box = (const float*)d_in[2];   // [3,3]    f32
  float* out = (float*)d_out;                 // scalar f32
  float* grid = (float*)d_ws;                 // 3360 floats
  double* acc = (double*)((char*)d_ws + ACC_BYTE_OFF); // 2 doubles

  zero_ws<<<(WS_WORDS + 255)/256, 256, 0, stream>>>((unsigned int*)d_ws);
  spread_kernel<<<NATOM/256, 256, 0, stream>>>(pos, chg, box, grid);
  modesum_kernel<<<KX, 256, 0, stream>>>(grid, box, acc);
  direct_kernel<<<dim3(NATOM/256, NATOM/256), 256, 0, stream>>>(pos, chg, box, acc);
  finalize_kernel<<<1, 256, 0, stream>>>(chg, box, acc, out);
}

// Round 2
// 134.516 us; speedup vs baseline: 1.4951x; 1.4951x over previous
//
#include <hip/hip_runtime.h>
#include <math.h>

// ---- Problem constants (baked into the reference) ----
#define NATOM 4096
#define KX 14
#define KY 15
#define KZ 16
#define NGRID (KX*KY*KZ)          // 3360
// ws layout: float grid[3360] at byte 0; double dpart[1024] at byte 13440
#define DPART_BYTE_OFF 13440

static constexpr float ALPHA_F   = 4.985823141035867f;
static constexpr float COULOMB_F = 138.935f;
static constexpr float CUT2_F    = 0.25f;    // CUTOFF^2
static constexpr float TWOPI_F   = 6.283185307179586f;
static constexpr float PI_F      = 3.14159265358979f;

// ---- Cardinal B-spline M5 via the Essmann recursion (matches reference _M) ----
__device__ __forceinline__ float M1f(float x){ return (x >= 0.f && x < 1.f) ? 1.f : 0.f; }
__device__ __forceinline__ float M2f(float x){ return x*M1f(x) + (2.f-x)*M1f(x-1.f); }
__device__ __forceinline__ float M3f(float x){ return (x*M2f(x) + (3.f-x)*M2f(x-1.f)) * 0.5f; }
__device__ __forceinline__ float M4f(float x){ return (x*M3f(x) + (4.f-x)*M3f(x-1.f)) * (1.f/3.f); }
__device__ __forceinline__ float M5f(float x){ return (x*M4f(x) + (5.f-x)*M4f(x-1.f)) * 0.25f; }

// ---- 3x3 inverse (general, though test box is diagonal) ----
__device__ __forceinline__ void inv3x3(const float* b, float* inv){
  float det = b[0]*(b[4]*b[8]-b[5]*b[7]) - b[1]*(b[3]*b[8]-b[5]*b[6]) + b[2]*(b[3]*b[7]-b[4]*b[6]);
  float id = 1.f/det;
  inv[0] = (b[4]*b[8]-b[5]*b[7])*id;
  inv[1] = (b[2]*b[7]-b[1]*b[8])*id;
  inv[2] = (b[1]*b[5]-b[2]*b[4])*id;
  inv[3] = (b[5]*b[6]-b[3]*b[8])*id;
  inv[4] = (b[0]*b[8]-b[2]*b[6])*id;
  inv[5] = (b[2]*b[3]-b[0]*b[5])*id;
  inv[6] = (b[3]*b[7]-b[4]*b[6])*id;
  inv[7] = (b[1]*b[6]-b[0]*b[7])*id;
  inv[8] = (b[0]*b[4]-b[1]*b[3])*id;
}

// ---- zero the mesh (only thing that needs pre-zeroing: spread uses atomics) ----
__global__ __launch_bounds__(256) void zero_ws(float* __restrict__ g){
  int i = blockIdx.x*256 + threadIdx.x;
  if (i < NGRID) g[i] = 0.f;
}

// ---- charge spreading: per-block LDS privatized grid, then global atomics ----
__global__ __launch_bounds__(256) void spread_kernel(const float* __restrict__ pos,
    const float* __restrict__ chg, const float* __restrict__ box, float* __restrict__ grid)
{
  __shared__ float sg[NGRID];
  for (int i = threadIdx.x; i < NGRID; i += 256) sg[i] = 0.f;
  __syncthreads();

  float b[9], inv[9];
  #pragma unroll
  for (int i = 0; i < 9; ++i) b[i] = box[i];
  inv3x3(b, inv);

  int atom = blockIdx.x*256 + threadIdx.x;
  float px = pos[atom*3+0], py = pos[atom*3+1], pz = pos[atom*3+2];
  float qi = chg[atom];
  float fr[3];
  fr[0] = px*inv[0] + py*inv[3] + pz*inv[6];
  fr[1] = px*inv[1] + py*inv[4] + pz*inv[7];
  fr[2] = px*inv[2] + py*inv[5] + pz*inv[8];

  const int Ks[3] = {KX, KY, KZ};
  float w[3][5]; int id[3][5];
  #pragma unroll
  for (int a = 0; a < 3; ++a) {
    float f = fr[a] - floorf(fr[a]);
    float u = f * (float)Ks[a];
    float bse = floorf(u);
    float x = u - bse;
    int bi = (int)bse;
    #pragma unroll
    for (int j = 0; j < 5; ++j) {
      w[a][j] = M5f(x + (float)j);           // weight for grid point (base - j)
      int ii = bi - j; if (ii < 0) ii += Ks[a];
      id[a][j] = ii;
    }
  }
  #pragma unroll
  for (int jx = 0; jx < 5; ++jx) {
    float qx = qi * w[0][jx];
    int ox = id[0][jx]*(KY*KZ);
    #pragma unroll
    for (int jy = 0; jy < 5; ++jy) {
      float qxy = qx * w[1][jy];
      int oxy = ox + id[1][jy]*KZ;
      #pragma unroll
      for (int jz = 0; jz < 5; ++jz)
        atomicAdd(&sg[oxy + id[2][jz]], qxy * w[2][jz]);
    }
  }
  __syncthreads();
  for (int i = threadIdx.x; i < NGRID; i += 256) {
    float v = sg[i];
    if (v != 0.f) atomicAdd(&grid[i], v);
  }
}

// ---- direct space: 256i x 64j tiles (1024 blocks), per-block double partial ----
__global__ __launch_bounds__(256) void direct_kernel(const float* __restrict__ pos,
    const float* __restrict__ chg, const float* __restrict__ box, double* __restrict__ dpart)
{
  __shared__ float sx[64], sy[64], sz[64], sw[64];
  __shared__ double red[4];
  int t  = threadIdx.x;
  int i  = blockIdx.x*256 + t;
  int j0 = blockIdx.y*64;
  if (t < 64){
    int j = j0 + t;
    sx[t] = pos[j*3+0]; sy[t] = pos[j*3+1]; sz[t] = pos[j*3+2]; sw[t] = chg[j];
  }
  __syncthreads();

  float b00=box[0],b01=box[1],b02=box[2],
        b10=box[3],b11=box[4],b12=box[5],
        b20=box[6],b21=box[7],b22=box[8];
  bool diag = (b01==0.f && b02==0.f && b10==0.f && b12==0.f && b20==0.f && b21==0.f);
  float i00 = 1.f/b00, i11 = 1.f/b11, i22 = 1.f/b22;

  float xi = pos[i*3+0], yi = pos[i*3+1], zi = pos[i*3+2], qi = chg[i];
  const float A2 = ALPHA_F*ALPHA_F;
  float e = 0.f;

  if (diag){
    #pragma unroll 4
    for (int jj = 0; jj < 64; ++jj){
      float dx = xi - sx[jj], dy = yi - sy[jj], dz = zi - sz[jj];
      dz -= b22*rintf(dz*i22);
      dy -= b11*rintf(dy*i11);
      dx -= b00*rintf(dx*i00);
      float r2 = dx*dx + dy*dy + dz*dz;
      if (r2 < CUT2_F && (j0 + jj) != i){
        // erfc(x) ~= t*(a1+t*(a2+t*(a3+t*(a4+t*a5))))*exp(-x^2), t=1/(1+p x)  (A&S 7.1.26, |e|<1.5e-7)
        float rinv = __builtin_amdgcn_rsqf(r2);       // 1/r
        float x = ALPHA_F * (r2 * rinv);              // alpha*r
        float tt = __builtin_amdgcn_rcpf(1.f + 0.3275911f*x);
        float poly = ((((1.061405429f*tt - 1.453152027f)*tt + 1.421413741f)*tt
                      - 0.284496736f)*tt + 0.254829592f)*tt;
        float ex = __expf(-A2*r2);                    // exp(-(alpha*r)^2)
        e += qi * sw[jj] * poly * ex * rinv;
      }
    }
  } else {
    for (int jj = 0; jj < 64; ++jj){
      float dx = xi - sx[jj], dy = yi - sy[jj], dz = zi - sz[jj];
      float t2 = rintf(dz * i22); dx -= b20*t2; dy -= b21*t2; dz -= b22*t2;
      float t1 = rintf(dy * i11); dx -= b10*t1; dy -= b11*t1; dz -= b12*t1;
      float t0 = rintf(dx * i00); dx -= b00*t0; dy -= b01*t0; dz -= b02*t0;
      float r2 = dx*dx + dy*dy + dz*dz;
      if (r2 < CUT2_F && (j0 + jj) != i){
        float r = sqrtf(r2);
        e += qi * sw[jj] * erfcf(ALPHA_F * r) / r;
      }
    }
  }

  double de = (double)e;
  #pragma unroll
  for (int off = 32; off > 0; off >>= 1) de += __shfl_down(de, off);
  if ((t & 63) == 0) red[t >> 6] = de;
  __syncthreads();
  if (t == 0) dpart[blockIdx.y*16 + blockIdx.x] = red[0]+red[1]+red[2]+red[3];
}

// ---- fused reciprocal (3-pass separable DFT in LDS) + final combine ----
// one block, 1024 threads, runs on 1 CU; total work ~1M FLOP + small LDS traffic
#define NT 1024
__global__ __launch_bounds__(NT) void recip_final_kernel(
    const float* __restrict__ grid, const float* __restrict__ chg,
    const float* __restrict__ box, const double* __restrict__ dpart,
    float* __restrict__ out)
{
  // arena layout (floats):
  //  [0,6720)       Cz  (float2[3360], z-DFT of mesh)          phase z out / y in
  //  [6720,10080)   sq  (real mesh)                            phase z in (dead after)
  //  [10080,10592)  Tz  (float2[16*16], [gz][mz])              phase z (dead after)
  //  [6720,13440)   Cy  (float2[3360])                         phase y out / x in (overwrites sq+Tz)
  //  [13440,13890)  Ty  (float2[15*15], [my][gy])
  //  [13890,14282)  Tx  (float2[14*14], [mx][gx])
  //  [14282,14327)  bmx[14] bmy[15] bmz[16]
  //  [14328,14424)  red (double[48]: 16 waves x {rec,dir,q2})
  __shared__ float arena[14424];
  float2* Cz  = (float2*)(arena);
  float*  sq  = arena + 6720;
  float2* Tz  = (float2*)(arena + 10080);
  float2* Cy  = (float2*)(arena + 6720);
  float2* Ty  = (float2*)(arena + 13440);
  float2* Tx  = (float2*)(arena + 13890);
  float*  bmx = arena + 14282;
  float*  bmy = arena + 14296;
  float*  bmz = arena + 14311;
  double* red = (double*)(arena + 14328);

  int t = threadIdx.x;

  // ---- phase 1: load mesh, build twiddle + |b(m)|^-2 tables ----
  for (int i = t; i < NGRID; i += NT) sq[i] = grid[i];
  for (int i = t; i < KZ*KZ; i += NT){             // Tz[gz][mz]
    int gz = i / KZ, mz = i % KZ;
    float s, c; __sincosf(-TWOPI_F*(float)((mz*gz)%KZ)/(float)KZ, &s, &c);
    Tz[i] = make_float2(c, s);
  }
  for (int i = t; i < KY*KY; i += NT){             // Ty[my][gy]
    int my = i / KY, gy = i % KY;
    float s, c; __sincosf(-TWOPI_F*(float)((my*gy)%KY)/(float)KY, &s, &c);
    Ty[i] = make_float2(c, s);
  }
  for (int i = t; i < KX*KX; i += NT){             // Tx[mx][gx]
    int mx = i / KX, gx = i % KX;
    float s, c; __sincosf(-TWOPI_F*(float)((mx*gx)%KX)/(float)KX, &s, &c);
    Tx[i] = make_float2(c, s);
  }
  // |b(m)|^-2 per axis: denom = (1 + 11 c1 + 11 c2 + c3)/24 + i(...)/24
  for (int i = t; i < KX+KY+KZ; i += NT){
    int m, K; float* dst;
    if (i < KX){ m = i; K = KX; dst = &bmx[i]; }
    else if (i < KX+KY){ m = i-KX; K = KY; dst = &bmy[m]; }
    else { m = i-KX-KY; K = KZ; dst = &bmz[m]; }
    float base = TWOPI_F*(float)m/(float)K, s, c;
    float dr = 1.f/24.f, di = 0.f;
    __sincosf(base,     &s, &c); dr += (11.f/24.f)*c; di += (11.f/24.f)*s;
    __sincosf(base*2.f, &s, &c); dr += (11.f/24.f)*c; di += (11.f/24.f)*s;
    __sincosf(base*3.f, &s, &c); dr += (1.f/24.f)*c;  di += (1.f/24.f)*s;
    float d2 = dr*dr + di*di;
    *dst = (d2 < 1e-7f) ? 0.f : 1.f/d2;
  }
  __syncthreads();

  // ---- pass z: Cz[gx][gy][mz] = sum_gz sq[gx][gy][gz] * e^{-2pi i mz gz/KZ} ----
  for (int i = t; i < NGRID; i += NT){
    int gx = i/(KY*KZ), r = i%(KY*KZ), gy = r/KZ, mz = r%KZ;
    const float* row = &sq[gx*(KY*KZ) + gy*KZ];
    float br = 0.f, bi = 0.f;
    #pragma unroll
    for (int gz = 0; gz < KZ; ++gz){
      float q = row[gz]; float2 w = Tz[gz*KZ + mz];
      br += q*w.x; bi += q*w.y;
    }
    Cz[i] = make_float2(br, bi);
  }
  __syncthreads();

  // ---- pass y: Cy[gx][my][mz] = sum_gy Cz[gx][gy][mz] * e^{-2pi i my gy/KY} ----
  for (int i = t; i < NGRID; i += NT){
    int gx = i/(KY*KZ), r = i%(KY*KZ), my = r/KZ, mz = r%KZ;
    float ar = 0.f, ai = 0.f;
    #pragma unroll
    for (int gy = 0; gy < KY; ++gy){
      float2 v = Cz[gx*(KY*KZ) + gy*KZ + mz];
      float2 w = Ty[my*KY + gy];
      ar += v.x*w.x - v.y*w.y;
      ai += v.x*w.y + v.y*w.x;
    }
    Cy[i] = make_float2(ar, ai);   // safe: overwrites sq/Tz region, Cz untouched
  }
  __syncthreads();

  // ---- pass x + green: sum_m green(m)*B(m)*|F(m)|^2 ----
  float b[9], inv[9];
  #pragma unroll
  for (int k = 0; k < 9; ++k) b[k] = box[k];
  inv3x3(b, inv);

  double s_rec = 0.0;
  for (int i = t; i < NGRID; i += NT){
    int mx = i/(KY*KZ), r = i%(KY*KZ), my = r/KZ, mz = r%KZ;
    float Fr = 0.f, Fi = 0.f;
    #pragma unroll
    for (int gx = 0; gx < KX; ++gx){
      float2 v = Cy[gx*(KY*KZ) + my*KZ + mz];
      float2 w = Tx[mx*KX + gx];
      Fr += v.x*w.x - v.y*w.y;
      Fi += v.x*w.y + v.y*w.x;
    }
    float fx = (mx <= (KX-1)/2) ? (float)mx : (float)(mx - KX);
    float fy = (my <= (KY-1)/2) ? (float)my : (float)(my - KY);
    float fz = (mz <= (KZ-1)/2) ? (float)mz : (float)(mz - KZ);
    float mv0 = fx*inv[0] + fy*inv[1] + fz*inv[2];
    float mv1 = fx*inv[3] + fy*inv[4] + fz*inv[5];
    float mv2 = fx*inv[6] + fy*inv[7] + fz*inv[8];
    float m2 = mv0*mv0 + mv1*mv1 + mv2*mv2;
    float B  = bmx[mx]*bmy[my]*bmz[mz];
    if (m2 > 0.f && B > 0.f){
      float green = expf(-(PI_F*PI_F)*m2/(ALPHA_F*ALPHA_F)) / m2;
      s_rec += (double)(green*B) * ((double)Fr*(double)Fr + (double)Fi*(double)Fi);
    }
  }

  // ---- direct partials + self-energy sum ----
  double s_dir = dpart[t];                       // NT == 1024 == #direct blocks
  double s_q2 = 0.0;
  for (int i = t; i < NATOM; i += NT){ double q = (double)chg[i]; s_q2 += q*q; }

  #pragma unroll
  for (int off = 32; off > 0; off >>= 1){
    s_rec += __shfl_down(s_rec, off);
    s_dir += __shfl_down(s_dir, off);
    s_q2  += __shfl_down(s_q2,  off);
  }
  int lane = t & 63, wid = t >> 6;
  if (lane == 0){ red[wid] = s_rec; red[16+wid] = s_dir; red[32+wid] = s_q2; }
  __syncthreads();

  if (t == 0){
    double R = 0.0, D = 0.0, Q = 0.0;
    for (int w = 0; w < 16; ++w){ R += red[w]; D += red[16+w]; Q += red[32+w]; }
    double b00=box[0],b01=box[1],b02=box[2],
           b10=box[3],b11=box[4],b12=box[5],
           b20=box[6],b21=box[7],b22=box[8];
    double det = b00*(b11*b22 - b12*b21) - b01*(b10*b22 - b12*b20) + b02*(b10*b21 - b11*b20);
    double V = fabs(det);
    const double PI_D = 3.141592653589793238462643;
    double edir  = 0.5 * (double)COULOMB_F * D;
    double erec  = (double)COULOMB_F / (2.0*PI_D*V) * R;
    double eself = -(double)COULOMB_F * 4.985823141035867 / sqrt(PI_D) * Q;
    out[0] = (float)(edir - erec - eself);
  }
}

extern "C" void kernel_launch(void* const* d_in, const int* in_sizes, int n_in,
                              void* d_out, int out_size, void* d_ws, size_t ws_size,
                              hipStream_t stream) {
  const float* pos = (const float*)d_in[0];   // [4096,3] f32
  const float* chg = (const float*)d_in[1];   // [4096]   f32
  const float* box = (const float*)d_in[2];   // [3,3]    f32
  float* out = (float*)d_out;                 // scalar f32
  float* grid = (float*)d_ws;                 // 3360 floats
  double* dpart = (double*)((char*)d_ws + DPART_BYTE_OFF); // 1024 doubles

  zero_ws<<<(NGRID + 255)/256, 256, 0, stream>>>(grid);
  spread_kernel<<<NATOM/256, 256, 0, stream>>>(pos, chg, box, grid);
  direct_kernel<<<dim3(16, 64), 256, 0, stream>>>(pos, chg, box, dpart);
  recip_final_kernel<<<1, NT, 0, stream>>>(grid, chg, box, dpart, out);
}

// Round 3
// 106.204 us; speedup vs baseline: 1.8937x; 1.2666x over previous
//
#include <hip/hip_runtime.h>
#include <math.h>

// ---- Problem constants (baked into the reference) ----
#define NATOM 4096
#define KX 14
#define KY 15
#define KZ 16
#define SLAB (KY*KZ)              // 240
#define NGRID (KX*SLAB)           // 3360

static constexpr float ALPHA_F   = 4.985823141035867f;
static constexpr float COULOMB_F = 138.935f;
static constexpr float CUT2_F    = 0.25f;    // CUTOFF^2
static constexpr float TWOPI_F   = 6.283185307179586f;
static constexpr float PI_F      = 3.14159265358979f;

// ---- Cardinal B-spline M5 via the Essmann recursion (matches reference _M) ----
__device__ __forceinline__ float M1f(float x){ return (x >= 0.f && x < 1.f) ? 1.f : 0.f; }
__device__ __forceinline__ float M2f(float x){ return x*M1f(x) + (2.f-x)*M1f(x-1.f); }
__device__ __forceinline__ float M3f(float x){ return (x*M2f(x) + (3.f-x)*M2f(x-1.f)) * 0.5f; }
__device__ __forceinline__ float M4f(float x){ return (x*M3f(x) + (4.f-x)*M3f(x-1.f)) * (1.f/3.f); }
__device__ __forceinline__ float M5f(float x){ return (x*M4f(x) + (5.f-x)*M4f(x-1.f)) * 0.25f; }

__device__ __forceinline__ void inv3x3(const float* b, float* inv){
  float det = b[0]*(b[4]*b[8]-b[5]*b[7]) - b[1]*(b[3]*b[8]-b[5]*b[6]) + b[2]*(b[3]*b[7]-b[4]*b[6]);
  float id = 1.f/det;
  inv[0] = (b[4]*b[8]-b[5]*b[7])*id;
  inv[1] = (b[2]*b[7]-b[1]*b[8])*id;
  inv[2] = (b[1]*b[5]-b[2]*b[4])*id;
  inv[3] = (b[5]*b[6]-b[3]*b[8])*id;
  inv[4] = (b[0]*b[8]-b[2]*b[6])*id;
  inv[5] = (b[2]*b[3]-b[0]*b[5])*id;
  inv[6] = (b[3]*b[7]-b[4]*b[6])*id;
  inv[7] = (b[1]*b[6]-b[0]*b[7])*id;
  inv[8] = (b[0]*b[4]-b[1]*b[3])*id;
}

// |b(m)|^-2 ; M5 at integers 1..4 = {1,11,11,1}/24; exact zeros at m=K/2 survive
// fast-sincos error (d2 ~ 1e-13 < 1e-7 cutoff).
__device__ __forceinline__ float bmod(int m, int K){
  float base = TWOPI_F * (float)m / (float)K;
  float s, c;
  float dr = 1.f/24.f, di = 0.f;
  __sincosf(base,      &s, &c); dr += (11.f/24.f)*c; di += (11.f/24.f)*s;
  __sincosf(base*2.f,  &s, &c); dr += (11.f/24.f)*c; di += (11.f/24.f)*s;
  __sincosf(base*3.f,  &s, &c); dr += (1.f/24.f)*c;  di += (1.f/24.f)*s;
  float d2 = dr*dr + di*di;
  return (d2 < 1e-7f) ? 0.f : 1.f/d2;
}

// ---- spread: NB blocks x (4096/NB) atoms; LDS private mesh -> private global copy ----
__global__ __launch_bounds__(64) void spread_kernel(const float* __restrict__ pos,
    const float* __restrict__ chg, const float* __restrict__ box,
    float* __restrict__ copies, int apb)
{
  __shared__ float sg[NGRID];
  int t = threadIdx.x;
  for (int i = t; i < NGRID; i += 64) sg[i] = 0.f;
  __syncthreads();

  float b[9], inv[9];
  #pragma unroll
  for (int i = 0; i < 9; ++i) b[i] = box[i];
  inv3x3(b, inv);

  for (int a = t; a < apb; a += 64){
    int atom = blockIdx.x*apb + a;
    float px = pos[atom*3+0], py = pos[atom*3+1], pz = pos[atom*3+2];
    float qi = chg[atom];
    float fr[3];
    fr[0] = px*inv[0] + py*inv[3] + pz*inv[6];
    fr[1] = px*inv[1] + py*inv[4] + pz*inv[7];
    fr[2] = px*inv[2] + py*inv[5] + pz*inv[8];

    const int Ks[3] = {KX, KY, KZ};
    float w[3][5]; int id[3][5];
    #pragma unroll
    for (int ax = 0; ax < 3; ++ax) {
      float f = fr[ax] - floorf(fr[ax]);
      float u = f * (float)Ks[ax];
      float bse = floorf(u);
      float x = u - bse;
      int bi = (int)bse;
      #pragma unroll
      for (int j = 0; j < 5; ++j) {
        w[ax][j] = M5f(x + (float)j);          // weight for grid point (base - j)
        int ii = bi - j; if (ii < 0) ii += Ks[ax];
        id[ax][j] = ii;
      }
    }
    #pragma unroll
    for (int jx = 0; jx < 5; ++jx) {
      float qx = qi * w[0][jx];
      int ox = id[0][jx]*SLAB;
      #pragma unroll
      for (int jy = 0; jy < 5; ++jy) {
        float qxy = qx * w[1][jy];
        int oxy = ox + id[1][jy]*KZ;
        #pragma unroll
        for (int jz = 0; jz < 5; ++jz)
          atomicAdd(&sg[oxy + id[2][jz]], qxy * w[2][jz]);
      }
    }
  }
  __syncthreads();
  float* dst = copies + (size_t)blockIdx.x*NGRID;
  for (int i = t; i < NGRID; i += 64) dst[i] = sg[i];
}

// ---- direct space: 256i x 64j tiles (1024 blocks), per-block double partial ----
__global__ __launch_bounds__(256) void direct_kernel(const float* __restrict__ pos,
    const float* __restrict__ chg, const float* __restrict__ box, double* __restrict__ dpart)
{
  __shared__ float sx[64], sy[64], sz[64], sw[64];
  __shared__ double red[4];
  int t  = threadIdx.x;
  int i  = blockIdx.x*256 + t;
  int j0 = blockIdx.y*64;
  if (t < 64){
    int j = j0 + t;
    sx[t] = pos[j*3+0]; sy[t] = pos[j*3+1]; sz[t] = pos[j*3+2]; sw[t] = chg[j];
  }
  __syncthreads();

  float b00=box[0],b01=box[1],b02=box[2],
        b10=box[3],b11=box[4],b12=box[5],
        b20=box[6],b21=box[7],b22=box[8];
  bool diag = (b01==0.f && b02==0.f && b10==0.f && b12==0.f && b20==0.f && b21==0.f);
  float i00 = 1.f/b00, i11 = 1.f/b11, i22 = 1.f/b22;

  float xi = pos[i*3+0], yi = pos[i*3+1], zi = pos[i*3+2], qi = chg[i];
  const float A2 = ALPHA_F*ALPHA_F;
  float e = 0.f;

  if (diag){
    #pragma unroll 4
    for (int jj = 0; jj < 64; ++jj){
      float dx = xi - sx[jj], dy = yi - sy[jj], dz = zi - sz[jj];
      dz -= b22*rintf(dz*i22);
      dy -= b11*rintf(dy*i11);
      dx -= b00*rintf(dx*i00);
      float r2 = dx*dx + dy*dy + dz*dz;
      if (r2 < CUT2_F && (j0 + jj) != i){
        // erfc(x) ~= t*poly(t)*exp(-x^2), t=1/(1+p x)  (A&S 7.1.26, |e|<1.5e-7)
        float rinv = __builtin_amdgcn_rsqf(r2);
        float x = ALPHA_F * (r2 * rinv);
        float tt = __builtin_amdgcn_rcpf(1.f + 0.3275911f*x);
        float poly = ((((1.061405429f*tt - 1.453152027f)*tt + 1.421413741f)*tt
                      - 0.284496736f)*tt + 0.254829592f)*tt;
        float ex = __expf(-A2*r2);
        e += qi * sw[jj] * poly * ex * rinv;
      }
    }
  } else {
    for (int jj = 0; jj < 64; ++jj){
      float dx = xi - sx[jj], dy = yi - sy[jj], dz = zi - sz[jj];
      float t2 = rintf(dz * i22); dx -= b20*t2; dy -= b21*t2; dz -= b22*t2;
      float t1 = rintf(dy * i11); dx -= b10*t1; dy -= b11*t1; dz -= b12*t1;
      float t0 = rintf(dx * i00); dx -= b00*t0; dy -= b01*t0; dz -= b02*t0;
      float r2 = dx*dx + dy*dy + dz*dz;
      if (r2 < CUT2_F && (j0 + jj) != i){
        float r = sqrtf(r2);
        e += qi * sw[jj] * erfcf(ALPHA_F * r) / r;
      }
    }
  }

  double de = (double)e;
  #pragma unroll
  for (int off = 32; off > 0; off >>= 1) de += __shfl_down(de, off);
  if ((t & 63) == 0) red[t >> 6] = de;
  __syncthreads();
  if (t == 0) dpart[blockIdx.y*16 + blockIdx.x] = red[0]+red[1]+red[2]+red[3];
}

// ---- recip part 1: per-gx slab: reduce NB copies, z-DFT, y-DFT -> Cy[gx][my][mz] ----
__global__ __launch_bounds__(256) void recip_zy_kernel(const float* __restrict__ copies,
    int nb, float2* __restrict__ Cy)
{
  __shared__ float  sq[SLAB];        // [gy][gz]
  __shared__ float2 Cz[SLAB];        // [gy][mz]
  __shared__ float2 Tz[KZ*KZ];       // [gz][mz]
  __shared__ float2 Ty[KY*KY];       // [my][gy]
  int t  = threadIdx.x;
  int gx = blockIdx.x;

  if (t < KZ*KZ){
    int gz = t / KZ, mz = t % KZ;
    float s, c; __sincosf(-TWOPI_F*(float)((gz*mz)%KZ)/(float)KZ, &s, &c);
    Tz[t] = make_float2(c, s);
  }
  if (t < KY*KY){
    int my = t / KY, gy = t % KY;
    float s, c; __sincosf(-TWOPI_F*(float)((my*gy)%KY)/(float)KY, &s, &c);
    Ty[t] = make_float2(c, s);
  }
  if (t < SLAB){
    float s = 0.f;
    const float* base = copies + (size_t)gx*SLAB + t;
    #pragma unroll 8
    for (int k = 0; k < nb; ++k) s += base[(size_t)k*NGRID];
    sq[t] = s;
  }
  __syncthreads();

  if (t < SLAB){                     // z-pass: out (gy,mz)
    int gy = t / KZ, mz = t % KZ;
    const float* row = &sq[gy*KZ];
    float br = 0.f, bi = 0.f;
    #pragma unroll
    for (int gz = 0; gz < KZ; ++gz){
      float q = row[gz]; float2 w = Tz[gz*KZ + mz];
      br += q*w.x; bi += q*w.y;
    }
    Cz[t] = make_float2(br, bi);
  }
  __syncthreads();

  if (t < SLAB){                     // y-pass: out (my,mz)
    int my = t / KZ, mz = t % KZ;
    float ar = 0.f, ai = 0.f;
    #pragma unroll
    for (int gy = 0; gy < KY; ++gy){
      float2 v = Cz[gy*KZ + mz];
      float2 w = Ty[my*KY + gy];
      ar += v.x*w.x - v.y*w.y;
      ai += v.x*w.y + v.y*w.x;
    }
    Cy[(size_t)gx*SLAB + t] = make_float2(ar, ai);
  }
}

// ---- recip part 2: x-DFT + green + direct partials + self energy -> out scalar ----
#define NT 1024
__global__ __launch_bounds__(NT) void recip_final_kernel(
    const float2* __restrict__ Cy, const float* __restrict__ chg,
    const float* __restrict__ box, const double* __restrict__ dpart,
    float* __restrict__ out)
{
  __shared__ float2 Tx[KX*KX];       // [mx][gx]
  __shared__ double red[48];
  int t = threadIdx.x;

  if (t < KX*KX){
    int mx = t / KX, gx = t % KX;
    float s, c; __sincosf(-TWOPI_F*(float)((mx*gx)%KX)/(float)KX, &s, &c);
    Tx[t] = make_float2(c, s);
  }
  __syncthreads();

  float b[9], inv[9];
  #pragma unroll
  for (int k = 0; k < 9; ++k) b[k] = box[k];
  inv3x3(b, inv);

  double s_rec = 0.0;
  for (int i = t; i < NGRID; i += NT){
    int mx = i / SLAB, r = i % SLAB, my = r / KZ, mz = r % KZ;
    float Fr = 0.f, Fi = 0.f;
    #pragma unroll
    for (int gx = 0; gx < KX; ++gx){
      float2 v = Cy[gx*SLAB + r];
      float2 w = Tx[mx*KX + gx];
      Fr += v.x*w.x - v.y*w.y;
      Fi += v.x*w.y + v.y*w.x;
    }
    float fx = (mx <= (KX-1)/2) ? (float)mx : (float)(mx - KX);
    float fy = (my <= (KY-1)/2) ? (float)my : (float)(my - KY);
    float fz = (mz <= (KZ-1)/2) ? (float)mz : (float)(mz - KZ);
    float mv0 = fx*inv[0] + fy*inv[1] + fz*inv[2];
    float mv1 = fx*inv[3] + fy*inv[4] + fz*inv[5];
    float mv2 = fx*inv[6] + fy*inv[7] + fz*inv[8];
    float m2 = mv0*mv0 + mv1*mv1 + mv2*mv2;
    float B  = bmod(mx,KX)*bmod(my,KY)*bmod(mz,KZ);
    if (m2 > 0.f && B > 0.f){
      float green = expf(-(PI_F*PI_F)*m2/(ALPHA_F*ALPHA_F)) / m2;
      s_rec += (double)(green*B) * ((double)Fr*(double)Fr + (double)Fi*(double)Fi);
    }
  }

  double s_dir = dpart[t];                       // NT == #direct blocks == 1024
  double s_q2 = 0.0;
  #pragma unroll
  for (int i = t; i < NATOM; i += NT){ double q = (double)chg[i]; s_q2 += q*q; }

  #pragma unroll
  for (int off = 32; off > 0; off >>= 1){
    s_rec += __shfl_down(s_rec, off);
    s_dir += __shfl_down(s_dir, off);
    s_q2  += __shfl_down(s_q2,  off);
  }
  int lane = t & 63, wid = t >> 6;
  if (lane == 0){ red[wid] = s_rec; red[16+wid] = s_dir; red[32+wid] = s_q2; }
  __syncthreads();

  if (t == 0){
    double R = 0.0, D = 0.0, Q = 0.0;
    for (int w = 0; w < 16; ++w){ R += red[w]; D += red[16+w]; Q += red[32+w]; }
    double b00=box[0],b01=box[1],b02=box[2],
           b10=box[3],b11=box[4],b12=box[5],
           b20=box[6],b21=box[7],b22=box[8];
    double det = b00*(b11*b22 - b12*b21) - b01*(b10*b22 - b12*b20) + b02*(b10*b21 - b11*b20);
    double V = fabs(det);
    const double PI_D = 3.141592653589793238462643;
    double edir  = 0.5 * (double)COULOMB_F * D;
    double erec  = (double)COULOMB_F / (2.0*PI_D*V) * R;
    double eself = -(double)COULOMB_F * 4.985823141035867 / sqrt(PI_D) * Q;
    out[0] = (float)(edir - erec - eself);
  }
}

extern "C" void kernel_launch(void* const* d_in, const int* in_sizes, int n_in,
                              void* d_out, int out_size, void* d_ws, size_t ws_size,
                              hipStream_t stream) {
  const float* pos = (const float*)d_in[0];   // [4096,3] f32
  const float* chg = (const float*)d_in[1];   // [4096]   f32
  const float* box = (const float*)d_in[2];   // [3,3]    f32
  float* out = (float*)d_out;

  // choose copy count to fit ws (deterministic in ws_size -> graph-safe)
  int nb = 128;
  size_t need;
  for (;;){
    need = (size_t)nb*NGRID*4 + 1024*8 + NGRID*8;
    if (need <= ws_size || nb <= 16) break;
    nb >>= 1;
  }
  int apb = NATOM / nb;

  float*  copies = (float*)d_ws;                                  // nb * 3360 f32
  double* dpart  = (double*)((char*)d_ws + (size_t)nb*NGRID*4);   // 1024 f64
  float2* Cy     = (float2*)((char*)dpart + 1024*8);              // 3360 cfloat

  spread_kernel<<<nb, 64, 0, stream>>>(pos, chg, box, copies, apb);
  direct_kernel<<<dim3(16, 64), 256, 0, stream>>>(pos, chg, box, dpart);
  recip_zy_kernel<<<KX, 256, 0, stream>>>(copies, nb, Cy);
  recip_final_kernel<<<1, NT, 0, stream>>>(Cy, chg, box, dpart, out);
}

// Round 4
// 104.350 us; speedup vs baseline: 1.9274x; 1.0178x over previous
//
#include <hip/hip_runtime.h>
#include <math.h>

// ---- Problem constants (baked into the reference) ----
#define NATOM 4096
#define KX 14
#define KY 15
#define KZ 16
#define SLAB (KY*KZ)              // 240
#define NGRID (KX*SLAB)           // 3360
#define NDIRECT 1024              // direct blocks (16 i-tiles x 64 j-tiles)

static constexpr float ALPHA_F   = 4.985823141035867f;
static constexpr float COULOMB_F = 138.935f;
static constexpr float CUT2_F    = 0.25f;    // CUTOFF^2
static constexpr float TWOPI_F   = 6.283185307179586f;
static constexpr float PI_F      = 3.14159265358979f;

// ---- Cardinal B-spline M5 via the Essmann recursion (matches reference _M) ----
__device__ __forceinline__ float M1f(float x){ return (x >= 0.f && x < 1.f) ? 1.f : 0.f; }
__device__ __forceinline__ float M2f(float x){ return x*M1f(x) + (2.f-x)*M1f(x-1.f); }
__device__ __forceinline__ float M3f(float x){ return (x*M2f(x) + (3.f-x)*M2f(x-1.f)) * 0.5f; }
__device__ __forceinline__ float M4f(float x){ return (x*M3f(x) + (4.f-x)*M3f(x-1.f)) * (1.f/3.f); }
__device__ __forceinline__ float M5f(float x){ return (x*M4f(x) + (5.f-x)*M4f(x-1.f)) * 0.25f; }

__device__ __forceinline__ void inv3x3(const float* b, float* inv){
  float det = b[0]*(b[4]*b[8]-b[5]*b[7]) - b[1]*(b[3]*b[8]-b[5]*b[6]) + b[2]*(b[3]*b[7]-b[4]*b[6]);
  float id = 1.f/det;
  inv[0] = (b[4]*b[8]-b[5]*b[7])*id;
  inv[1] = (b[2]*b[7]-b[1]*b[8])*id;
  inv[2] = (b[1]*b[5]-b[2]*b[4])*id;
  inv[3] = (b[5]*b[6]-b[3]*b[8])*id;
  inv[4] = (b[0]*b[8]-b[2]*b[6])*id;
  inv[5] = (b[2]*b[3]-b[0]*b[5])*id;
  inv[6] = (b[3]*b[7]-b[4]*b[6])*id;
  inv[7] = (b[1]*b[6]-b[0]*b[7])*id;
  inv[8] = (b[0]*b[4]-b[1]*b[3])*id;
}

// |b(m)|^-2 ; M5 at integers 1..4 = {1,11,11,1}/24; exact zeros at odd-order m=K/2
__device__ __forceinline__ float bmod(int m, int K){
  float base = TWOPI_F * (float)m / (float)K;
  float s, c;
  float dr = 1.f/24.f, di = 0.f;
  __sincosf(base,      &s, &c); dr += (11.f/24.f)*c; di += (11.f/24.f)*s;
  __sincosf(base*2.f,  &s, &c); dr += (11.f/24.f)*c; di += (11.f/24.f)*s;
  __sincosf(base*3.f,  &s, &c); dr += (1.f/24.f)*c;  di += (1.f/24.f)*s;
  float d2 = dr*dr + di*di;
  return (d2 < 1e-7f) ? 0.f : 1.f/d2;
}

// ================= fat kernel: direct tiles (blocks 0..1023) + spread (1024..1023+nb) ====
__global__ __launch_bounds__(256) void fat_kernel(const float* __restrict__ pos,
    const float* __restrict__ chg, const float* __restrict__ box,
    float* __restrict__ copies, double* __restrict__ dpart, int nb, int apb)
{
  __shared__ float sg[NGRID];         // spread branch (13.4 KB)
  __shared__ float sx[64], sy[64], sz[64], sw[64];
  __shared__ double red4[4];
  int t = threadIdx.x;
  int b = blockIdx.x;

  if (b < NDIRECT){
    // ---------------- direct-space tile: 256 i x 64 j ----------------
    int i  = (b & 15)*256 + t;
    int j0 = (b >> 4)*64;
    if (t < 64){
      int j = j0 + t;
      sx[t] = pos[j*3+0]; sy[t] = pos[j*3+1]; sz[t] = pos[j*3+2]; sw[t] = chg[j];
    }
    __syncthreads();

    float b00=box[0],b01=box[1],b02=box[2],
          b10=box[3],b11=box[4],b12=box[5],
          b20=box[6],b21=box[7],b22=box[8];
    bool diag = (b01==0.f && b02==0.f && b10==0.f && b12==0.f && b20==0.f && b21==0.f);
    float i00 = 1.f/b00, i11 = 1.f/b11, i22 = 1.f/b22;

    float xi = pos[i*3+0], yi = pos[i*3+1], zi = pos[i*3+2], qi = chg[i];
    const float A2 = ALPHA_F*ALPHA_F;
    float e = 0.f;

    if (diag){
      #pragma unroll 4
      for (int jj = 0; jj < 64; ++jj){
        float dx = xi - sx[jj], dy = yi - sy[jj], dz = zi - sz[jj];
        dz -= b22*rintf(dz*i22);
        dy -= b11*rintf(dy*i11);
        dx -= b00*rintf(dx*i00);
        float r2 = dx*dx + dy*dy + dz*dz;
        if (r2 < CUT2_F && (j0 + jj) != i){
          // erfc(x) ~= t*poly(t)*exp(-x^2), t=1/(1+p x)  (A&S 7.1.26, |e|<1.5e-7)
          float rinv = __builtin_amdgcn_rsqf(r2);
          float x = ALPHA_F * (r2 * rinv);
          float tt = __builtin_amdgcn_rcpf(1.f + 0.3275911f*x);
          float poly = ((((1.061405429f*tt - 1.453152027f)*tt + 1.421413741f)*tt
                        - 0.284496736f)*tt + 0.254829592f)*tt;
          float ex = __expf(-A2*r2);
          e += qi * sw[jj] * poly * ex * rinv;
        }
      }
    } else {
      for (int jj = 0; jj < 64; ++jj){
        float dx = xi - sx[jj], dy = yi - sy[jj], dz = zi - sz[jj];
        float t2 = rintf(dz * i22); dx -= b20*t2; dy -= b21*t2; dz -= b22*t2;
        float t1 = rintf(dy * i11); dx -= b10*t1; dy -= b11*t1; dz -= b12*t1;
        float t0 = rintf(dx * i00); dx -= b00*t0; dy -= b01*t0; dz -= b02*t0;
        float r2 = dx*dx + dy*dy + dz*dz;
        if (r2 < CUT2_F && (j0 + jj) != i){
          float r = sqrtf(r2);
          e += qi * sw[jj] * erfcf(ALPHA_F * r) / r;
        }
      }
    }

    double de = (double)e;
    #pragma unroll
    for (int off = 32; off > 0; off >>= 1) de += __shfl_down(de, off);
    if ((t & 63) == 0) red4[t >> 6] = de;
    __syncthreads();
    if (t == 0) dpart[b] = red4[0]+red4[1]+red4[2]+red4[3];

  } else {
    // ---------------- spread: apb atoms -> private LDS mesh -> private copy ----------------
    int sb = b - NDIRECT;
    for (int i = t; i < NGRID; i += 256) sg[i] = 0.f;
    __syncthreads();

    float bx[9], inv[9];
    #pragma unroll
    for (int i = 0; i < 9; ++i) bx[i] = box[i];
    inv3x3(bx, inv);

    for (int a = t; a < apb; a += 256){
      int atom = sb*apb + a;
      float px = pos[atom*3+0], py = pos[atom*3+1], pz = pos[atom*3+2];
      float qi = chg[atom];
      float fr[3];
      fr[0] = px*inv[0] + py*inv[3] + pz*inv[6];
      fr[1] = px*inv[1] + py*inv[4] + pz*inv[7];
      fr[2] = px*inv[2] + py*inv[5] + pz*inv[8];

      const int Ks[3] = {KX, KY, KZ};
      float w[3][5]; int id[3][5];
      #pragma unroll
      for (int ax = 0; ax < 3; ++ax) {
        float f = fr[ax] - floorf(fr[ax]);
        float u = f * (float)Ks[ax];
        float bse = floorf(u);
        float x = u - bse;
        int bi = (int)bse;
        #pragma unroll
        for (int j = 0; j < 5; ++j) {
          w[ax][j] = M5f(x + (float)j);          // weight for grid point (base - j)
          int ii = bi - j; if (ii < 0) ii += Ks[ax];
          id[ax][j] = ii;
        }
      }
      #pragma unroll
      for (int jx = 0; jx < 5; ++jx) {
        float qx = qi * w[0][jx];
        int ox = id[0][jx]*SLAB;
        #pragma unroll
        for (int jy = 0; jy < 5; ++jy) {
          float qxy = qx * w[1][jy];
          int oxy = ox + id[1][jy]*KZ;
          #pragma unroll
          for (int jz = 0; jz < 5; ++jz)
            atomicAdd(&sg[oxy + id[2][jz]], qxy * w[2][jz]);
        }
      }
    }
    __syncthreads();
    float* dst = copies + (size_t)sb*NGRID;
    for (int i = t; i < NGRID; i += 256) dst[i] = sg[i];
  }
}

// ====== recip kernel: blocks 0..13 = copy-reduce + z/y DFT (publish Cy + flag);
//        block 14 spins on flags, then x-DFT + green + final combine ======
__global__ __launch_bounds__(256) void recip_kernel(const float* __restrict__ copies,
    int nb, const float* __restrict__ chg, const float* __restrict__ box,
    const double* __restrict__ dpart, float2* __restrict__ Cy,
    int* __restrict__ flags, float* __restrict__ out)
{
  __shared__ float  sq[SLAB];        // [gy][gz]
  __shared__ float2 Cz[SLAB];        // [gy][mz]
  __shared__ float2 Tz[KZ*KZ];       // [gz][mz]
  __shared__ float2 Ty[KY*KY];       // [my][gy]
  __shared__ float2 sCy[NGRID];      // final block: whole Cy (26.9 KB)
  __shared__ float2 Tx[KX*KX];       // [mx][gx]
  __shared__ double red[12];
  int t = threadIdx.x;
  int b = blockIdx.x;

  if (b < KX){
    // ---------------- per-gx slab: reduce nb copies, z-DFT, y-DFT ----------------
    int gx = b;
    if (t < KZ*KZ){
      int gz = t / KZ, mz = t % KZ;
      float s, c; __sincosf(-TWOPI_F*(float)((gz*mz)%KZ)/(float)KZ, &s, &c);
      Tz[t] = make_float2(c, s);
    }
    if (t < KY*KY){
      int my = t / KY, gy = t % KY;
      float s, c; __sincosf(-TWOPI_F*(float)((my*gy)%KY)/(float)KY, &s, &c);
      Ty[t] = make_float2(c, s);
    }
    if (t < SLAB){
      float s = 0.f;
      const float* base = copies + (size_t)gx*SLAB + t;
      #pragma unroll 8
      for (int k = 0; k < nb; ++k) s += base[(size_t)k*NGRID];
      sq[t] = s;
    }
    __syncthreads();

    if (t < SLAB){                     // z-pass: (gy,gz) -> (gy,mz)
      int gy = t / KZ, mz = t % KZ;
      const float* row = &sq[gy*KZ];
      float br = 0.f, bi = 0.f;
      #pragma unroll
      for (int gz = 0; gz < KZ; ++gz){
        float q = row[gz]; float2 w = Tz[gz*KZ + mz];
        br += q*w.x; bi += q*w.y;
      }
      Cz[t] = make_float2(br, bi);
    }
    __syncthreads();

    if (t < SLAB){                     // y-pass: (gy,mz) -> (my,mz)
      int my = t / KZ, mz = t % KZ;
      float ar = 0.f, ai = 0.f;
      #pragma unroll
      for (int gy = 0; gy < KY; ++gy){
        float2 v = Cz[gy*KZ + mz];
        float2 w = Ty[my*KY + gy];
        ar += v.x*w.x - v.y*w.y;
        ai += v.x*w.y + v.y*w.x;
      }
      Cy[(size_t)gx*SLAB + t] = make_float2(ar, ai);
    }
    __threadfence();                   // publish Cy (device scope)
    __syncthreads();
    if (t == 0)
      __hip_atomic_store(&flags[gx], 1, __ATOMIC_RELEASE, __HIP_MEMORY_SCOPE_AGENT);

  } else {
    // ---------------- final: wait for all 14 slabs, then x-DFT + green + combine ----------------
    if (t < KX*KX){
      int mx = t / KX, gx = t % KX;
      float s, c; __sincosf(-TWOPI_F*(float)((mx*gx)%KX)/(float)KX, &s, &c);
      Tx[t] = make_float2(c, s);
    }
    if (t < KX){
      while (__hip_atomic_load(&flags[t], __ATOMIC_ACQUIRE, __HIP_MEMORY_SCOPE_AGENT) != 1) { }
    }
    __syncthreads();
    __threadfence();                   // acquire: no stale Cy in caches

    for (int i = t; i < NGRID; i += 256) sCy[i] = Cy[i];
    __syncthreads();

    float bx[9], inv[9];
    #pragma unroll
    for (int k = 0; k < 9; ++k) bx[k] = box[k];
    inv3x3(bx, inv);

    double s_rec = 0.0;
    for (int i = t; i < NGRID; i += 256){
      int mx = i / SLAB, r = i % SLAB, my = r / KZ, mz = r % KZ;
      float Fr = 0.f, Fi = 0.f;
      #pragma unroll
      for (int gx = 0; gx < KX; ++gx){
        float2 v = sCy[gx*SLAB + r];
        float2 w = Tx[mx*KX + gx];
        Fr += v.x*w.x - v.y*w.y;
        Fi += v.x*w.y + v.y*w.x;
      }
      float fx = (mx <= (KX-1)/2) ? (float)mx : (float)(mx - KX);
      float fy = (my <= (KY-1)/2) ? (float)my : (float)(my - KY);
      float fz = (mz <= (KZ-1)/2) ? (float)mz : (float)(mz - KZ);
      float mv0 = fx*inv[0] + fy*inv[1] + fz*inv[2];
      float mv1 = fx*inv[3] + fy*inv[4] + fz*inv[5];
      float mv2 = fx*inv[6] + fy*inv[7] + fz*inv[8];
      float m2 = mv0*mv0 + mv1*mv1 + mv2*mv2;
      float B  = bmod(mx,KX)*bmod(my,KY)*bmod(mz,KZ);
      if (m2 > 0.f && B > 0.f){
        float green = expf(-(PI_F*PI_F)*m2/(ALPHA_F*ALPHA_F)) / m2;
        s_rec += (double)(green*B) * ((double)Fr*(double)Fr + (double)Fi*(double)Fi);
      }
    }

    double s_dir = 0.0;
    #pragma unroll
    for (int k = 0; k < NDIRECT/256; ++k) s_dir += dpart[t + k*256];
    double s_q2 = 0.0;
    for (int i = t; i < NATOM; i += 256){ double q = (double)chg[i]; s_q2 += q*q; }

    #pragma unroll
    for (int off = 32; off > 0; off >>= 1){
      s_rec += __shfl_down(s_rec, off);
      s_dir += __shfl_down(s_dir, off);
      s_q2  += __shfl_down(s_q2,  off);
    }
    int lane = t & 63, wid = t >> 6;
    if (lane == 0){ red[wid] = s_rec; red[4+wid] = s_dir; red[8+wid] = s_q2; }
    __syncthreads();

    if (t == 0){
      double R = red[0]+red[1]+red[2]+red[3];
      double D = red[4]+red[5]+red[6]+red[7];
      double Q = red[8]+red[9]+red[10]+red[11];
      double b00=box[0],b01=box[1],b02=box[2],
             b10=box[3],b11=box[4],b12=box[5],
             b20=box[6],b21=box[7],b22=box[8];
      double det = b00*(b11*b22 - b12*b21) - b01*(b10*b22 - b12*b20) + b02*(b10*b21 - b11*b20);
      double V = fabs(det);
      const double PI_D = 3.141592653589793238462643;
      double edir  = 0.5 * (double)COULOMB_F * D;
      double erec  = (double)COULOMB_F / (2.0*PI_D*V) * R;
      double eself = -(double)COULOMB_F * 4.985823141035867 / sqrt(PI_D) * Q;
      out[0] = (float)(edir - erec - eself);
    }
  }
}

extern "C" void kernel_launch(void* const* d_in, const int* in_sizes, int n_in,
                              void* d_out, int out_size, void* d_ws, size_t ws_size,
                              hipStream_t stream) {
  const float* pos = (const float*)d_in[0];   // [4096,3] f32
  const float* chg = (const float*)d_in[1];   // [4096]   f32
  const float* box = (const float*)d_in[2];   // [3,3]    f32
  float* out = (float*)d_out;

  // copy count chosen from ws_size only (deterministic -> graph-safe)
  int nb = 128;
  for (;;){
    size_t need = (size_t)nb*NGRID*4 + NDIRECT*8 + NGRID*8 + 64;
    if (need <= ws_size || nb <= 16) break;
    nb >>= 1;
  }
  int apb = NATOM / nb;

  float*  copies = (float*)d_ws;                                   // nb * 3360 f32
  double* dpart  = (double*)((char*)d_ws + (size_t)nb*NGRID*4);    // 1024 f64
  float2* Cy     = (float2*)((char*)dpart + NDIRECT*8);            // 3360 cfloat
  int*    flags  = (int*)((char*)Cy + NGRID*8);                    // 14 ints (poison 0xAA != 1)

  fat_kernel<<<NDIRECT + nb, 256, 0, stream>>>(pos, chg, box, copies, dpart, nb, apb);
  recip_kernel<<<KX + 1, 256, 0, stream>>>(copies, nb, chg, box, dpart, Cy, flags, out);
}

// Round 5
// 97.006 us; speedup vs baseline: 2.0733x; 1.0757x over previous
//
#include <hip/hip_runtime.h>
#include <math.h>

// ---- Problem constants (baked into the reference) ----
#define NATOM 4096
#define KX 14
#define KY 15
#define KZ 16
#define SLAB (KY*KZ)              // 240
#define NGRID (KX*SLAB)           // 3360
#define NDIRECT 1024              // direct blocks (16 i-tiles x 64 j-tiles)

static constexpr float ALPHA_F   = 4.985823141035867f;
static constexpr float COULOMB_F = 138.935f;
static constexpr float CUT2_F    = 0.25f;    // CUTOFF^2
static constexpr float TWOPI_F   = 6.283185307179586f;
static constexpr float PI_F      = 3.14159265358979f;

// ---- Cardinal B-spline M5 via the Essmann recursion (matches reference _M) ----
__device__ __forceinline__ float M1f(float x){ return (x >= 0.f && x < 1.f) ? 1.f : 0.f; }
__device__ __forceinline__ float M2f(float x){ return x*M1f(x) + (2.f-x)*M1f(x-1.f); }
__device__ __forceinline__ float M3f(float x){ return (x*M2f(x) + (3.f-x)*M2f(x-1.f)) * 0.5f; }
__device__ __forceinline__ float M4f(float x){ return (x*M3f(x) + (4.f-x)*M3f(x-1.f)) * (1.f/3.f); }
__device__ __forceinline__ float M5f(float x){ return (x*M4f(x) + (5.f-x)*M4f(x-1.f)) * 0.25f; }

__device__ __forceinline__ void inv3x3(const float* b, float* inv){
  float det = b[0]*(b[4]*b[8]-b[5]*b[7]) - b[1]*(b[3]*b[8]-b[5]*b[6]) + b[2]*(b[3]*b[7]-b[4]*b[6]);
  float id = 1.f/det;
  inv[0] = (b[4]*b[8]-b[5]*b[7])*id;
  inv[1] = (b[2]*b[7]-b[1]*b[8])*id;
  inv[2] = (b[1]*b[5]-b[2]*b[4])*id;
  inv[3] = (b[5]*b[6]-b[3]*b[8])*id;
  inv[4] = (b[0]*b[8]-b[2]*b[6])*id;
  inv[5] = (b[2]*b[3]-b[0]*b[5])*id;
  inv[6] = (b[3]*b[7]-b[4]*b[6])*id;
  inv[7] = (b[1]*b[6]-b[0]*b[7])*id;
  inv[8] = (b[0]*b[4]-b[1]*b[3])*id;
}

// |b(m)|^-2 ; M5 at integers 1..4 = {1,11,11,1}/24; exact zeros at odd-order m=K/2
__device__ __forceinline__ float bmod(int m, int K){
  float base = TWOPI_F * (float)m / (float)K;
  float s, c;
  float dr = 1.f/24.f, di = 0.f;
  __sincosf(base,      &s, &c); dr += (11.f/24.f)*c; di += (11.f/24.f)*s;
  __sincosf(base*2.f,  &s, &c); dr += (11.f/24.f)*c; di += (11.f/24.f)*s;
  __sincosf(base*3.f,  &s, &c); dr += (1.f/24.f)*c;  di += (1.f/24.f)*s;
  float d2 = dr*dr + di*di;
  return (d2 < 1e-7f) ? 0.f : 1.f/d2;
}

// ================= fat kernel: direct tiles (blocks 0..1023) + spread (1024..1023+nb) ====
__global__ __launch_bounds__(256) void fat_kernel(const float* __restrict__ pos,
    const float* __restrict__ chg, const float* __restrict__ box,
    float* __restrict__ copies, double* __restrict__ dpart, int nb, int apb)
{
  __shared__ float sg[NGRID];         // spread branch (13.4 KB)
  __shared__ float sx[64], sy[64], sz[64], sw[64];
  __shared__ double red4[4];
  int t = threadIdx.x;
  int b = blockIdx.x;

  if (b < NDIRECT){
    // ---------------- direct-space tile: 256 i x 64 j ----------------
    int i  = (b & 15)*256 + t;
    int j0 = (b >> 4)*64;
    if (t < 64){
      int j = j0 + t;
      sx[t] = pos[j*3+0]; sy[t] = pos[j*3+1]; sz[t] = pos[j*3+2]; sw[t] = chg[j];
    }
    __syncthreads();

    float b00=box[0],b01=box[1],b02=box[2],
          b10=box[3],b11=box[4],b12=box[5],
          b20=box[6],b21=box[7],b22=box[8];
    bool diag = (b01==0.f && b02==0.f && b10==0.f && b12==0.f && b20==0.f && b21==0.f);
    float i00 = 1.f/b00, i11 = 1.f/b11, i22 = 1.f/b22;

    float xi = pos[i*3+0], yi = pos[i*3+1], zi = pos[i*3+2], qi = chg[i];
    const float A2 = ALPHA_F*ALPHA_F;
    float e = 0.f;

    if (diag){
      #pragma unroll 4
      for (int jj = 0; jj < 64; ++jj){
        float dx = xi - sx[jj], dy = yi - sy[jj], dz = zi - sz[jj];
        dz -= b22*rintf(dz*i22);
        dy -= b11*rintf(dy*i11);
        dx -= b00*rintf(dx*i00);
        float r2 = dx*dx + dy*dy + dz*dz;
        if (r2 < CUT2_F && (j0 + jj) != i){
          // erfc(x) ~= t*poly(t)*exp(-x^2), t=1/(1+p x)  (A&S 7.1.26, |e|<1.5e-7)
          float rinv = __builtin_amdgcn_rsqf(r2);
          float x = ALPHA_F * (r2 * rinv);
          float tt = __builtin_amdgcn_rcpf(1.f + 0.3275911f*x);
          float poly = ((((1.061405429f*tt - 1.453152027f)*tt + 1.421413741f)*tt
                        - 0.284496736f)*tt + 0.254829592f)*tt;
          float ex = __expf(-A2*r2);
          e += qi * sw[jj] * poly * ex * rinv;
        }
      }
    } else {
      for (int jj = 0; jj < 64; ++jj){
        float dx = xi - sx[jj], dy = yi - sy[jj], dz = zi - sz[jj];
        float t2 = rintf(dz * i22); dx -= b20*t2; dy -= b21*t2; dz -= b22*t2;
        float t1 = rintf(dy * i11); dx -= b10*t1; dy -= b11*t1; dz -= b12*t1;
        float t0 = rintf(dx * i00); dx -= b00*t0; dy -= b01*t0; dz -= b02*t0;
        float r2 = dx*dx + dy*dy + dz*dz;
        if (r2 < CUT2_F && (j0 + jj) != i){
          float r = sqrtf(r2);
          e += qi * sw[jj] * erfcf(ALPHA_F * r) / r;
        }
      }
    }

    double de = (double)e;
    #pragma unroll
    for (int off = 32; off > 0; off >>= 1) de += __shfl_down(de, off);
    if ((t & 63) == 0) red4[t >> 6] = de;
    __syncthreads();
    if (t == 0) dpart[b] = red4[0]+red4[1]+red4[2]+red4[3];

  } else {
    // ---------------- spread: apb atoms -> private LDS mesh -> private copy ----------------
    int sb = b - NDIRECT;
    for (int i = t; i < NGRID; i += 256) sg[i] = 0.f;
    __syncthreads();

    float bx[9], inv[9];
    #pragma unroll
    for (int i = 0; i < 9; ++i) bx[i] = box[i];
    inv3x3(bx, inv);

    for (int a = t; a < apb; a += 256){
      int atom = sb*apb + a;
      float px = pos[atom*3+0], py = pos[atom*3+1], pz = pos[atom*3+2];
      float qi = chg[atom];
      float fr[3];
      fr[0] = px*inv[0] + py*inv[3] + pz*inv[6];
      fr[1] = px*inv[1] + py*inv[4] + pz*inv[7];
      fr[2] = px*inv[2] + py*inv[5] + pz*inv[8];

      const int Ks[3] = {KX, KY, KZ};
      float w[3][5]; int id[3][5];
      #pragma unroll
      for (int ax = 0; ax < 3; ++ax) {
        float f = fr[ax] - floorf(fr[ax]);
        float u = f * (float)Ks[ax];
        float bse = floorf(u);
        float x = u - bse;
        int bi = (int)bse;
        #pragma unroll
        for (int j = 0; j < 5; ++j) {
          w[ax][j] = M5f(x + (float)j);          // weight for grid point (base - j)
          int ii = bi - j; if (ii < 0) ii += Ks[ax];
          id[ax][j] = ii;
        }
      }
      #pragma unroll
      for (int jx = 0; jx < 5; ++jx) {
        float qx = qi * w[0][jx];
        int ox = id[0][jx]*SLAB;
        #pragma unroll
        for (int jy = 0; jy < 5; ++jy) {
          float qxy = qx * w[1][jy];
          int oxy = ox + id[1][jy]*KZ;
          #pragma unroll
          for (int jz = 0; jz < 5; ++jz)
            atomicAdd(&sg[oxy + id[2][jz]], qxy * w[2][jz]);
        }
      }
    }
    __syncthreads();
    float* dst = copies + (size_t)sb*NGRID;
    for (int i = t; i < NGRID; i += 256) dst[i] = sg[i];
  }
}

// ====== recip kernel (1024 threads/block):
//   blocks 0..13: 4 k-groups reduce nb/4 copies each -> LDS partials -> z/y DFT -> Cy+flag
//   block 14: spin on flags, x-DFT + green + final combine ======
#define RT 1024
__global__ __launch_bounds__(RT) void recip_kernel(const float* __restrict__ copies,
    int nb, const float* __restrict__ chg, const float* __restrict__ box,
    const double* __restrict__ dpart, float2* __restrict__ Cy,
    int* __restrict__ flags, float* __restrict__ out)
{
  __shared__ float  part[4][SLAB];   // per-k-group partial meshes
  __shared__ float  sq[SLAB];        // [gy][gz]
  __shared__ float2 Cz[SLAB];        // [gy][mz]
  __shared__ float2 Tz[KZ*KZ];       // [gz][mz]
  __shared__ float2 Ty[KY*KY];       // [my][gy]
  __shared__ float2 sCy[NGRID];      // final block: whole Cy (26.9 KB)
  __shared__ float2 Tx[KX*KX];       // [mx][gx]
  __shared__ double red[48];
  int t = threadIdx.x;
  int b = blockIdx.x;

  if (b < KX){
    // ---------------- per-gx slab ----------------
    int gx = b;
    if (t < KZ*KZ){
      int gz = t / KZ, mz = t % KZ;
      float s, c; __sincosf(-TWOPI_F*(float)((gz*mz)%KZ)/(float)KZ, &s, &c);
      Tz[t] = make_float2(c, s);
    }
    if (t >= 256 && t < 256 + KY*KY){
      int u = t - 256;
      int my = u / KY, gy = u % KY;
      float s, c; __sincosf(-TWOPI_F*(float)((my*gy)%KY)/(float)KY, &s, &c);
      Ty[u] = make_float2(c, s);
    }
    {
      // copy-reduce: group g sums copies [g*kq, (g+1)*kq) for cell u
      int g = t >> 8, u = t & 255;
      int kq = nb >> 2;
      if (u < SLAB){
        float s = 0.f;
        const float* base = copies + (size_t)(g*kq)*NGRID + (size_t)gx*SLAB + u;
        #pragma unroll 8
        for (int k = 0; k < kq; ++k) s += base[(size_t)k*NGRID];
        part[g][u] = s;
      }
    }
    __syncthreads();
    if (t < SLAB) sq[t] = part[0][t] + part[1][t] + part[2][t] + part[3][t];
    __syncthreads();

    if (t < SLAB){                     // z-pass: (gy,gz) -> (gy,mz)
      int gy = t / KZ, mz = t % KZ;
      const float* row = &sq[gy*KZ];
      float br = 0.f, bi = 0.f;
      #pragma unroll
      for (int gz = 0; gz < KZ; ++gz){
        float q = row[gz]; float2 w = Tz[gz*KZ + mz];
        br += q*w.x; bi += q*w.y;
      }
      Cz[t] = make_float2(br, bi);
    }
    __syncthreads();

    if (t < SLAB){                     // y-pass: (gy,mz) -> (my,mz)
      int my = t / KZ, mz = t % KZ;
      float ar = 0.f, ai = 0.f;
      #pragma unroll
      for (int gy = 0; gy < KY; ++gy){
        float2 v = Cz[gy*KZ + mz];
        float2 w = Ty[my*KY + gy];
        ar += v.x*w.x - v.y*w.y;
        ai += v.x*w.y + v.y*w.x;
      }
      Cy[(size_t)gx*SLAB + t] = make_float2(ar, ai);
    }
    __threadfence();                   // publish Cy (device scope)
    __syncthreads();
    if (t == 0)
      __hip_atomic_store(&flags[gx], 1, __ATOMIC_RELEASE, __HIP_MEMORY_SCOPE_AGENT);

  } else {
    // ---------------- final: wait for all 14 slabs, then x-DFT + green + combine ----------------
    if (t < KX*KX){
      int mx = t / KX, gx = t % KX;
      float s, c; __sincosf(-TWOPI_F*(float)((mx*gx)%KX)/(float)KX, &s, &c);
      Tx[t] = make_float2(c, s);
    }
    if (t < KX){
      while (__hip_atomic_load(&flags[t], __ATOMIC_ACQUIRE, __HIP_MEMORY_SCOPE_AGENT) != 1) { }
    }
    __syncthreads();
    __threadfence();                   // acquire side: no stale Cy

    for (int i = t; i < NGRID; i += RT) sCy[i] = Cy[i];
    __syncthreads();

    float bx[9], inv[9];
    #pragma unroll
    for (int k = 0; k < 9; ++k) bx[k] = box[k];
    inv3x3(bx, inv);

    double s_rec = 0.0;
    for (int i = t; i < NGRID; i += RT){
      int mx = i / SLAB, r = i % SLAB, my = r / KZ, mz = r % KZ;
      float Fr = 0.f, Fi = 0.f;
      #pragma unroll
      for (int gx = 0; gx < KX; ++gx){
        float2 v = sCy[gx*SLAB + r];
        float2 w = Tx[mx*KX + gx];
        Fr += v.x*w.x - v.y*w.y;
        Fi += v.x*w.y + v.y*w.x;
      }
      float fx = (mx <= (KX-1)/2) ? (float)mx : (float)(mx - KX);
      float fy = (my <= (KY-1)/2) ? (float)my : (float)(my - KY);
      float fz = (mz <= (KZ-1)/2) ? (float)mz : (float)(mz - KZ);
      float mv0 = fx*inv[0] + fy*inv[1] + fz*inv[2];
      float mv1 = fx*inv[3] + fy*inv[4] + fz*inv[5];
      float mv2 = fx*inv[6] + fy*inv[7] + fz*inv[8];
      float m2 = mv0*mv0 + mv1*mv1 + mv2*mv2;
      float B  = bmod(mx,KX)*bmod(my,KY)*bmod(mz,KZ);
      if (m2 > 0.f && B > 0.f){
        float green = expf(-(PI_F*PI_F)*m2/(ALPHA_F*ALPHA_F)) / m2;
        s_rec += (double)(green*B) * ((double)Fr*(double)Fr + (double)Fi*(double)Fi);
      }
    }

    double s_dir = dpart[t];           // RT == NDIRECT == 1024
    double s_q2 = 0.0;
    #pragma unroll
    for (int i = t; i < NATOM; i += RT){ double q = (double)chg[i]; s_q2 += q*q; }

    #pragma unroll
    for (int off = 32; off > 0; off >>= 1){
      s_rec += __shfl_down(s_rec, off);
      s_dir += __shfl_down(s_dir, off);
      s_q2  += __shfl_down(s_q2,  off);
    }
    int lane = t & 63, wid = t >> 6;
    if (lane == 0){ red[wid] = s_rec; red[16+wid] = s_dir; red[32+wid] = s_q2; }
    __syncthreads();

    if (t == 0){
      double R = 0.0, D = 0.0, Q = 0.0;
      for (int w = 0; w < 16; ++w){ R += red[w]; D += red[16+w]; Q += red[32+w]; }
      double b00=box[0],b01=box[1],b02=box[2],
             b10=box[3],b11=box[4],b12=box[5],
             b20=box[6],b21=box[7],b22=box[8];
      double det = b00*(b11*b22 - b12*b21) - b01*(b10*b22 - b12*b20) + b02*(b10*b21 - b11*b20);
      double V = fabs(det);
      const double PI_D = 3.141592653589793238462643;
      double edir  = 0.5 * (double)COULOMB_F * D;
      double erec  = (double)COULOMB_F / (2.0*PI_D*V) * R;
      double eself = -(double)COULOMB_F * 4.985823141035867 / sqrt(PI_D) * Q;
      out[0] = (float)(edir - erec - eself);
    }
  }
}

extern "C" void kernel_launch(void* const* d_in, const int* in_sizes, int n_in,
                              void* d_out, int out_size, void* d_ws, size_t ws_size,
                              hipStream_t stream) {
  const float* pos = (const float*)d_in[0];   // [4096,3] f32
  const float* chg = (const float*)d_in[1];   // [4096]   f32
  const float* box = (const float*)d_in[2];   // [3,3]    f32
  float* out = (float*)d_out;

  // copy count chosen from ws_size only (deterministic -> graph-safe)
  int nb = 128;
  for (;;){
    size_t need = (size_t)nb*NGRID*4 + NDIRECT*8 + NGRID*8 + 64;
    if (need <= ws_size || nb <= 16) break;
    nb >>= 1;
  }
  int apb = NATOM / nb;

  float*  copies = (float*)d_ws;                                   // nb * 3360 f32
  double* dpart  = (double*)((char*)d_ws + (size_t)nb*NGRID*4);    // 1024 f64
  float2* Cy     = (float2*)((char*)dpart + NDIRECT*8);            // 3360 cfloat
  int*    flags  = (int*)((char*)Cy + NGRID*8);                    // 14 ints (poison 0xAA != 1)

  fat_kernel<<<NDIRECT + nb, 256, 0, stream>>>(pos, chg, box, copies, dpart, nb, apb);
  recip_kernel<<<KX + 1, RT, 0, stream>>>(copies, nb, chg, box, dpart, Cy, flags, out);
}